// Round 13
// baseline (194.709 us; speedup 1.0000x reference)
//
#include <hip/hip_runtime.h>

// DIAGNOSTIC (correctness-preserving): measure per-replay fixed overhead h.
// Dispatch the best kernel (R10: tiny blocks + nt + 1 block/CU) TWICE in the
// same graph. Both dispatches write identical data -> output unchanged.
//   wall(R10)   = h + dev(R10)            = 99.8 us  (measured R10)
//   wall(this)  = h + 2*dev(R10) + gap
//   => dev(R10) ~= wall(this) - 99.8,  h ~= 99.8 - dev(R10).
// From R6 composite: dev(fill533, same 533 MB, plain) = 88.0 us exactly.
// Decision: dev(R10) <= ~92 -> R10 is at the same-size fill floor, declare
// roofline with R10 as final. dev(R10) ~= 99 -> h~=0, keep optimizing.

typedef float f32x4 __attribute__((ext_vector_type(4)));

constexpr unsigned Bn = 128;
constexpr unsigned Nn = 128;
constexpr unsigned NE = Nn * (Nn - 1);   // 16256
constexpr unsigned F4 = 16;              // f32x4 per 64-float row

__global__ __launch_bounds__(256) void node_edge_bcast_1cu(
    const f32x4* __restrict__ x, f32x4* __restrict__ out) {
    // 96 KB LDS -> at most 1 resident block per CU (160 KB pool).
    __shared__ f32x4 occupancy_pad[6144];

    const unsigned blk  = blockIdx.x;        // = b*Nn + node
    const unsigned tid  = threadIdx.x;
    const unsigned f4   = tid & (F4 - 1);    // feature quad 0..15
    const unsigned row0 = tid >> 4;          // starting replica row 0..15

    const f32x4 v = x[blk * F4 + f4];

    const unsigned b    = blk >> 7;          // / Nn
    const unsigned node = blk & (Nn - 1);    // % Nn
    f32x4* dst = out + (b * NE + node * (Nn - 1)) * F4;

    #pragma unroll
    for (unsigned r = row0; r < Nn - 1; r += 16) {
        __builtin_nontemporal_store(v, &dst[r * F4 + f4]);
    }

    // Keep the LDS allocation live; never executes.
    if (blk == 0xFFFFFFFFu) {
        occupancy_pad[tid] = v;
        __syncthreads();
        dst[0] = occupancy_pad[255 - tid];
    }
}

extern "C" void kernel_launch(void* const* d_in, const int* in_sizes, int n_in,
                              void* d_out, int out_size, void* d_ws, size_t ws_size,
                              hipStream_t stream) {
    const f32x4* x = (const f32x4*)d_in[0];
    f32x4* out = (f32x4*)d_out;

    // Same kernel twice: second dispatch rewrites identical values.
    node_edge_bcast_1cu<<<Bn * Nn, 256, 0, stream>>>(x, out);
    node_edge_bcast_1cu<<<Bn * Nn, 256, 0, stream>>>(x, out);
}

// Round 14
// 100.953 us; speedup vs baseline: 1.9287x; 1.9287x over previous
//
#include <hip/hip_runtime.h>

// NodeEdgeProjection: out[b, e, f] = x[b, e/127, f]
// B=128, N=128, n_edges=128*127, F=64, fp32. 533 MB written, 4 MB read.
//
// Ladder (wall us): R10 tiny+nt+1blk/CU 99.8 [dev 94.9, h=4.9 via R13
// double-dispatch] | R3 tiny+nt+8/CU 103.1 | R12 persistent 105.7 | others
// 106-120 | fill533 floor dev 88.0.
//
// R13 quantified the residual: dev(R10) - dev(fill) = 7 us. Candidate: at
// 1 block/CU the 64 blocks per CU run SEQUENTIALLY, each opening with an
// unhidden ~250 cy row load = 64*250/2.4GHz ~= 6.7 us. Matches.
//
// Round-13: residency = 2 (last untested point on that axis; 8/CU=103.1,
// 1/CU=99.8). Co-resident block B's startup load hides under block A's
// store drain. Window widens 8->16 MB (weak effect at small multiples).
// Single variable vs R10: LDS pad 96 KB -> 80 KB.

typedef float f32x4 __attribute__((ext_vector_type(4)));

constexpr unsigned Bn = 128;
constexpr unsigned Nn = 128;
constexpr unsigned NE = Nn * (Nn - 1);   // 16256
constexpr unsigned F4 = 16;              // f32x4 per 64-float row

__global__ __launch_bounds__(256) void node_edge_bcast_2cu(
    const f32x4* __restrict__ x, f32x4* __restrict__ out) {
    // 80 KB LDS -> exactly 2 resident blocks per CU (160 KB pool).
    __shared__ f32x4 occupancy_pad[5120];

    const unsigned blk  = blockIdx.x;        // = b*Nn + node
    const unsigned tid  = threadIdx.x;
    const unsigned f4   = tid & (F4 - 1);    // feature quad 0..15
    const unsigned row0 = tid >> 4;          // starting replica row 0..15

    const f32x4 v = x[blk * F4 + f4];

    const unsigned b    = blk >> 7;          // / Nn
    const unsigned node = blk & (Nn - 1);    // % Nn
    f32x4* dst = out + (b * NE + node * (Nn - 1)) * F4;

    #pragma unroll
    for (unsigned r = row0; r < Nn - 1; r += 16) {
        __builtin_nontemporal_store(v, &dst[r * F4 + f4]);
    }

    // Keep the LDS allocation live; never executes (blockIdx range is
    // opaque to the compiler so this isn't provably dead).
    if (blk == 0xFFFFFFFFu) {
        occupancy_pad[tid] = v;
        __syncthreads();
        dst[0] = occupancy_pad[255 - tid];
    }
}

extern "C" void kernel_launch(void* const* d_in, const int* in_sizes, int n_in,
                              void* d_out, int out_size, void* d_ws, size_t ws_size,
                              hipStream_t stream) {
    const f32x4* x = (const f32x4*)d_in[0];
    f32x4* out = (f32x4*)d_out;

    node_edge_bcast_2cu<<<Bn * Nn, 256, 0, stream>>>(x, out);
}

// Round 15
// 98.772 us; speedup vs baseline: 1.9713x; 1.0221x over previous
//
#include <hip/hip_runtime.h>

// NodeEdgeProjection: out[b, e, f] = x[b, e/127, f]
// B=128, N=128, n_edges=128*127, F=64, fp32. 533 MB written, 4 MB read.
//
// FINAL KERNEL = R10 (best of 11 measured variants).
// Ladder (wall us; h=4.9 replay overhead via R13 double-dispatch):
//   R10 tiny+nt+1blk/CU   99.8  [dev 94.9]  <- this kernel
//   R14 tiny+nt+2blk/CU  101.0
//   R3  tiny+nt+8blk/CU  103.1
//   R12 persistent        105.7 | R4 fat+plain 106.6 | R9 256-streams 106.0
//   R4' fat+nt 113.6 | R11 tiny+plain+1cu 113.1 | R1 stride 117.2
//   R5 1024-streams 119.7 | R8 pipelined-gs 197.3
//   fill533 (same-size pure fill) dev floor: 88.0 us.
// Confirmed levers: instantaneous write-window tightness (1 blk/CU, 8 MB
// rolling window); nt stores at LOW residency only (nt x residency
// interaction: +13 us at 1/CU, -7 us at 8/CU); store-only inner loop with
// the row value preloaded into registers.
// Residual dev gap vs fill (+7.8%): 16384 x 256 B scattered row reads
// interleaved into the write stream (read/write turnaround + per-block
// dependent load at 1/CU) -- intrinsic to the gather; all structural
// attempts to hide it (R12 persistent prefetch, R14 residency=2) regressed.

typedef float f32x4 __attribute__((ext_vector_type(4)));

constexpr unsigned Bn = 128;
constexpr unsigned Nn = 128;
constexpr unsigned NE = Nn * (Nn - 1);   // 16256
constexpr unsigned F4 = 16;              // f32x4 per 64-float row

__global__ __launch_bounds__(256) void node_edge_bcast_1cu(
    const f32x4* __restrict__ x, f32x4* __restrict__ out) {
    // 96 KB LDS -> at most 1 resident block per CU (160 KB pool).
    __shared__ f32x4 occupancy_pad[6144];

    const unsigned blk  = blockIdx.x;        // = b*Nn + node
    const unsigned tid  = threadIdx.x;
    const unsigned f4   = tid & (F4 - 1);    // feature quad 0..15
    const unsigned row0 = tid >> 4;          // starting replica row 0..15

    // One 256 B row per block, 16-way lane broadcast; store loop is
    // load-free with the value held in a register.
    const f32x4 v = x[blk * F4 + f4];

    const unsigned b    = blk >> 7;          // / Nn
    const unsigned node = blk & (Nn - 1);    // % Nn
    f32x4* dst = out + (b * NE + node * (Nn - 1)) * F4;

    // 127 replica rows; each iteration is a block-wide contiguous 4 KB
    // nontemporal store burst (nt wins at 1 blk/CU residency).
    #pragma unroll
    for (unsigned r = row0; r < Nn - 1; r += 16) {
        __builtin_nontemporal_store(v, &dst[r * F4 + f4]);
    }

    // Keep the LDS allocation live; never executes (blockIdx range is
    // opaque to the compiler so this isn't provably dead).
    if (blk == 0xFFFFFFFFu) {
        occupancy_pad[tid] = v;
        __syncthreads();
        dst[0] = occupancy_pad[255 - tid];
    }
}

extern "C" void kernel_launch(void* const* d_in, const int* in_sizes, int n_in,
                              void* d_out, int out_size, void* d_ws, size_t ws_size,
                              hipStream_t stream) {
    const f32x4* x = (const f32x4*)d_in[0];
    f32x4* out = (f32x4*)d_out;

    node_edge_bcast_1cu<<<Bn * Nn, 256, 0, stream>>>(x, out);
}